// Round 8
// baseline (221.608 us; speedup 1.0000x reference)
//
#include <hip/hip_runtime.h>
#include <math.h>

#define JN 4096
#define CN 8192

typedef __attribute__((ext_vector_type(8))) short short8;
typedef __attribute__((ext_vector_type(4))) short short4v;
typedef __attribute__((ext_vector_type(4))) float f32x4;

// ---- d_ws layout (float offsets) ----
#define WS_LWT    0        // bf16 8192*64 = 262144 float slots
#define WS_GTB    262144   // bf16 4096*64 = 131072 float slots
#define WS_ROWSUM 393216   // 4096
#define WS_DEG    397312   // 4096
#define WS_NORM   401408   // 4096
#define WS_X      405504   // 24576
#define WS_F1     430080   // 24576
#define WS_PART   454656   // 2*2048
#define WS_BAR    458752   // 4 uints (grid-barrier counters, zeroed by k_front)

// ---- scratch inside the Poss half of d_out (float offsets within Poss) ----
// All consumed before k_valueB overwrites the Poss region.
#define PS_BITR    0        // uint64[4096][64] = 2 MiB
#define PS_COLPART 524288   // 16*4096
#define PS_P1      589824   // 16*24576
#define PS_P2      983040   // 16*24576

__device__ __forceinline__ unsigned short f2bf(float x) {
    unsigned int u = __float_as_uint(x);
    u += 0x7fffu + ((u >> 16) & 1u);   // RNE
    return (unsigned short)(u >> 16);
}

__device__ __forceinline__ float gt_val(const float* __restrict__ x, const float* __restrict__ a,
                                        const float* __restrict__ b, const float* __restrict__ tw,
                                        float acc, int f) {
#pragma unroll
    for (int k = 0; k < 6; ++k) acc += x[k] * tw[k * 64 + f];
#pragma unroll
    for (int k = 0; k < 6; ++k) acc += a[k] * tw[(k + 6) * 64 + f];
#pragma unroll
    for (int k = 0; k < 6; ++k) acc += b[k] * tw[(k + 12) * 64 + f];
    return acc;
}

// device-scope grid barrier for a 256-block grid (all blocks provably co-resident:
// 21 KB LDS / 4 waves per block => capacity >= 8 blocks/CU * 256 CUs >> 256).
__device__ __forceinline__ void gbar(unsigned* c) {
    __syncthreads();
    if (threadIdx.x == 0) {
        __threadfence();   // release: make this block's global writes device-visible
        __hip_atomic_fetch_add(c, 1u, __ATOMIC_RELEASE, __HIP_MEMORY_SCOPE_AGENT);
        while (__hip_atomic_load(c, __ATOMIC_ACQUIRE, __HIP_MEMORY_SCOPE_AGENT) < 256u) {}
        __threadfence();
    }
    __syncthreads();
}

// ---------- front: G pass (rowsum+bitpack) | rank | lwT transpose | barrier init ----------
// bit layout: col cu -> word (cu>>10)*16 + ((cu>>8)&3)*4 + (cu&3), bit (cu>>2)&63
__global__ __launch_bounds__(256) void k_front(const float* __restrict__ G,
                                               const float* __restrict__ h, const float* __restrict__ L,
                                               const float* __restrict__ Wp, const float* __restrict__ Pp,
                                               const float* __restrict__ Np,
                                               const float* __restrict__ lw,
                                               float* __restrict__ rowsum,
                                               unsigned long long* __restrict__ bitR,
                                               float* __restrict__ X,
                                               unsigned short* __restrict__ lwT,
                                               unsigned* __restrict__ bar) {
    __shared__ float redf[4];
    __shared__ int redi[4];
    __shared__ float s_t[64][65];
    int wv = threadIdx.x >> 6, lane = threadIdx.x & 63;
    if (blockIdx.x < JN) {
        int row = blockIdx.x;
        const f32x4* g4 = (const f32x4*)(G + (size_t)row * CN);
        unsigned long long* brow = bitR + (size_t)row * 64;
        float s = 0.f;
#pragma unroll
        for (int i = 0; i < 4; ++i) {          // left half
            f32x4 v = __builtin_nontemporal_load(&g4[i * 256 + wv * 64 + lane]);
            s += v[0] + v[1] + v[2] + v[3];
            unsigned long long b0 = __ballot(v[0] != 0.f);
            unsigned long long b1 = __ballot(v[1] != 0.f);
            unsigned long long b2 = __ballot(v[2] != 0.f);
            unsigned long long b3 = __ballot(v[3] != 0.f);
            if (!lane) {
                int base = i * 16 + wv * 4;
                brow[base] = b0; brow[base + 1] = b1; brow[base + 2] = b2; brow[base + 3] = b3;
            }
        }
#pragma unroll
        for (int i = 4; i < 8; ++i) {          // right half
            f32x4 v = __builtin_nontemporal_load(&g4[i * 256 + wv * 64 + lane]);
            s += v[0] + v[1] + v[2] + v[3];
        }
        for (int o = 32; o; o >>= 1) s += __shfl_down(s, o, 64);
        if (!lane) redf[wv] = s;
        __syncthreads();
        if (!threadIdx.x) rowsum[row] = redf[0] + redf[1] + redf[2] + redf[3];
    } else if (blockIdx.x < 2 * JN) {
        int i = blockIdx.x - JN;
        float hi = h[i];
        int cnt = 0;
        for (int j = threadIdx.x; j < JN; j += 256) {
            float hj = h[j];
            cnt += (hj > hi) || (hj == hi && j < i);   // stable argsort(-h) rank
        }
        for (int o = 32; o; o >>= 1) cnt += __shfl_down(cnt, o, 64);
        if (!lane) redi[wv] = cnt;
        __syncthreads();
        if (!threadIdx.x) {
            int r = redi[0] + redi[1] + redi[2] + redi[3];
            float* xr = X + r * 6;
            xr[0] = hi; xr[1] = L[i]; xr[2] = *Wp; xr[3] = *Pp; xr[4] = *Np; xr[5] = 1.f;
        }
    } else if (blockIdx.x < 2 * JN + 128) {
        int c0 = (blockIdx.x - 2 * JN) * 64;
        for (int t = threadIdx.x; t < 4096; t += 256) {
            int f = t >> 6, cc = t & 63;
            s_t[f][cc] = lw[(size_t)f * CN + c0 + cc];
        }
        __syncthreads();
        for (int q = threadIdx.x; q < 512; q += 256) {
            int c = q >> 3, kc = q & 7;
            short8 pack;
#pragma unroll
            for (int i = 0; i < 8; ++i) pack[i] = (short)f2bf(s_t[kc * 8 + i][c]);
            *(short8*)(lwT + ((size_t)(c0 + c)) * 64 + kc * 8) = pack;
        }
    } else {
        if (threadIdx.x < 4) bar[threadIdx.x] = 0u;   // barrier counters init
    }
}

// ---------- middle (fused): colsum -> prop1 -> prop2 -> gt, grid-barriered ----------
__global__ __launch_bounds__(256) void k_middle(const unsigned long long* __restrict__ bitR,
                                                const float* __restrict__ X,
                                                const float* __restrict__ tw, const float* __restrict__ tb,
                                                float* __restrict__ colpart,
                                                float* __restrict__ deg, float* __restrict__ norm,
                                                float* __restrict__ f1,
                                                float* __restrict__ p1, float* __restrict__ p2,
                                                unsigned short* __restrict__ Gtb,
                                                unsigned* __restrict__ bar) {
    __shared__ unsigned long long s_bits[256][4];  // staged ONCE, reused by 3 phases
    __shared__ float s_in[1536];
    __shared__ float s_norm[256];
    __shared__ float s_tw[1152];
    __shared__ float s_tb[64];
    __shared__ float s_x[96], s_a[96], s_b[96];

    int tid = threadIdx.x;
    int b = blockIdx.x;
    int bx = b & 15, by = b >> 4;
    int r0 = by * 256;

    // ---- phase 1: colsum partials (cols bx*256.., rows r0..) ----
    for (int t = tid; t < 1024; t += 256) {
        int r = t >> 2, wl = t & 3;
        s_bits[r][wl] = bitR[(size_t)(r0 + r) * 64 + bx * 4 + wl];
    }
    __syncthreads();
    {
        int wl = tid & 3, bit = tid >> 2;
        int cnt = 0;
        for (int r = 0; r < 256; ++r)
            cnt += (int)((s_bits[r][wl] >> bit) & 1ull);
        colpart[(size_t)by * JN + bx * 256 + tid] = (float)cnt;
    }
    gbar(&bar[0]);

    // ---- phase 2: prop1 (reuses s_bits) ----
    {
        float d = 0.f;
        for (int ch = 0; ch < 16; ++ch) d += colpart[(size_t)ch * JN + r0 + tid];
        float dc = d < 1.f ? 1.f : d;
        float nv = rsqrtf(dc);
        s_norm[tid] = nv;
        if (bx == 0) { deg[r0 + tid] = d; norm[r0 + tid] = nv; }
    }
    __syncthreads();
    for (int t = tid; t < 1536; t += 256)
        s_in[t] = X[r0 * 6 + t] * s_norm[t / 6];
    __syncthreads();
    {
        int wl = tid & 3, bit = tid >> 2;
        float a0 = 0, a1 = 0, a2 = 0, a3 = 0, a4 = 0, a5 = 0;
        for (int r = 0; r < 256; ++r) {
            float g = (float)((s_bits[r][wl] >> bit) & 1ull);
            const float* x = &s_in[r * 6];
            a0 += g * x[0]; a1 += g * x[1]; a2 += g * x[2];
            a3 += g * x[3]; a4 += g * x[4]; a5 += g * x[5];
        }
        float* o = p1 + ((size_t)by * JN + bx * 256 + tid) * 6;
        o[0] = a0; o[1] = a1; o[2] = a2; o[3] = a3; o[4] = a4; o[5] = a5;
    }
    gbar(&bar[1]);

    // ---- phase 3: prop2 (reuses s_bits, s_norm) ----
    for (int t = tid; t < 1536; t += 256) {
        float s = 0.f;
        for (int ch = 0; ch < 16; ++ch) s += p1[(size_t)ch * 24576 + r0 * 6 + t];
        float n = s_norm[t / 6];
        float f1v = s * n;
        if (bx == 0) f1[r0 * 6 + t] = f1v;
        s_in[t] = f1v * n;
    }
    __syncthreads();
    {
        int wl = tid & 3, bit = tid >> 2;
        float a0 = 0, a1 = 0, a2 = 0, a3 = 0, a4 = 0, a5 = 0;
        for (int r = 0; r < 256; ++r) {
            float g = (float)((s_bits[r][wl] >> bit) & 1ull);
            const float* x = &s_in[r * 6];
            a0 += g * x[0]; a1 += g * x[1]; a2 += g * x[2];
            a3 += g * x[3]; a4 += g * x[4]; a5 += g * x[5];
        }
        float* o = p2 + ((size_t)by * JN + bx * 256 + tid) * 6;
        o[0] = a0; o[1] = a1; o[2] = a2; o[3] = a3; o[4] = a4; o[5] = a5;
    }
    gbar(&bar[2]);

    // ---- phase 4: Gt for rows j0 = b*16 .. +15 ----
    for (int t = tid; t < 1152; t += 256) s_tw[t] = tw[t];
    if (tid < 64) s_tb[tid] = tb[tid];
    {
        int j0 = b * 16;
        for (int t = tid; t < 96; t += 256) {
            s_x[t] = X[j0 * 6 + t];
            s_a[t] = f1[j0 * 6 + t];
            float s = 0.f;
            for (int ch = 0; ch < 16; ++ch) s += p2[(size_t)ch * 24576 + j0 * 6 + t];
            s_b[t] = s * norm[j0 + t / 6];
        }
        __syncthreads();
        int row = tid >> 4, fi = tid & 15;
        float xv[6], av[6], bv[6];
#pragma unroll
        for (int k = 0; k < 6; ++k) {
            xv[k] = s_x[row * 6 + k]; av[k] = s_a[row * 6 + k]; bv[k] = s_b[row * 6 + k];
        }
        short4v pk;
#pragma unroll
        for (int i = 0; i < 4; ++i) {
            int f = fi * 4 + i;
            float acc = gt_val(xv, av, bv, s_tw, s_tb[f], f);
            pk[i] = (short)f2bf(acc);
        }
        *(short4v*)(Gtb + (size_t)(j0 + row) * 64 + fi * 4) = pk;
    }
}

// Shared GEMM body: stage lwT + Gtb tiles (swizzled), swapped-operand MFMA.
// A = lw cols (M=c), B = Gt rows (N=j)  =>  lane's 4 C-regs = 4 consecutive cols.
#define GEMM_PROLOGUE()                                                                   \
    __shared__ unsigned short sGt[64 * 64];                                               \
    __shared__ unsigned short sW[256 * 64];                                               \
    int j0 = blockIdx.y * 64, c0 = blockIdx.x * 256, tid = threadIdx.x;                   \
    for (int q = tid; q < 2048; q += 256) {                                               \
        int col = q >> 3, off = q & 7;                                                    \
        short8 v = *(const short8*)(lwT + ((size_t)(c0 + col)) * 64 + off * 8);           \
        int byte = (col * 128 + off * 16) ^ ((col & 7) << 4);                             \
        *(short8*)((char*)sW + byte) = v;                                                 \
    }                                                                                     \
    for (int q = tid; q < 512; q += 256) {                                                \
        int row = q >> 3, off = q & 7;                                                    \
        short8 v = *(const short8*)(Gtb + ((size_t)(j0 + row)) * 64 + off * 8);           \
        int byte = (row * 128 + off * 16) ^ ((row & 7) << 4);                             \
        *(short8*)((char*)sGt + byte) = v;                                                \
    }                                                                                     \
    __syncthreads();                                                                      \
    int lane = tid & 63, w = tid >> 6;                                                    \
    int lrow = lane & 15, kg = lane >> 4;                                                 \
    f32x4 acc[4][4]; /* [m over c][n over j] */                                           \
    for (int m = 0; m < 4; ++m)                                                           \
        for (int n = 0; n < 4; ++n) acc[m][n] = (f32x4){0.f, 0.f, 0.f, 0.f};              \
    for (int ks = 0; ks < 2; ++ks) {                                                      \
        int kb = ks * 64 + kg * 16;                                                       \
        short8 wf[4], gf[4];                                                              \
        for (int m = 0; m < 4; ++m) {                                                     \
            int col = w * 64 + m * 16 + lrow;                                             \
            wf[m] = *(const short8*)((const char*)sW + ((col * 128 + kb) ^ ((col & 7) << 4))); \
        }                                                                                 \
        for (int n = 0; n < 4; ++n) {                                                     \
            int row = n * 16 + lrow;                                                      \
            gf[n] = *(const short8*)((const char*)sGt + ((row * 128 + kb) ^ ((row & 7) << 4))); \
        }                                                                                 \
        for (int m = 0; m < 4; ++m)                                                       \
            for (int n = 0; n < 4; ++n)                                                   \
                acc[m][n] = __builtin_amdgcn_mfma_f32_16x16x32_bf16(wf[m], gf[n], acc[m][n], 0, 0, 0); \
    }                                                                                     \
    bool left = (c0 < JN);                                                                \
    int cb[4]; f32x4 lb4[4], rsc4[4], dgc4[4];                                            \
    for (int m = 0; m < 4; ++m) {                                                         \
        cb[m] = c0 + w * 64 + m * 16 + kg * 4;                                            \
        lb4[m] = *(const f32x4*)&lb[cb[m]];                                               \
        if (left) { rsc4[m] = *(const f32x4*)&rowsum[cb[m]]; dgc4[m] = *(const f32x4*)&deg[cb[m]]; } \
        else      { rsc4[m] = (f32x4){0,0,0,0}; dgc4[m] = (f32x4){0,0,0,0}; }             \
    }

// ---------- pass A: Value write (nt float4) + two-pass softmax partials ----------
__global__ __launch_bounds__(256) void k_valueA(const unsigned short* __restrict__ Gtb,
                                                const unsigned short* __restrict__ lwT,
                                                const float* __restrict__ lb,
                                                const float* __restrict__ rowsum, const float* __restrict__ deg,
                                                float* __restrict__ Value, float* __restrict__ partials) {
    GEMM_PROLOGUE()
    __shared__ float sRedM[4], sRedS[4];

    float mx = -INFINITY;
#pragma unroll
    for (int n = 0; n < 4; ++n) {
        int j = j0 + n * 16 + lrow;
        float rs_i = rowsum[j], dg_i = deg[j];
#pragma unroll
        for (int m = 0; m < 4; ++m) {
            f32x4 v4 = acc[m][n] + lb4[m];
            __builtin_nontemporal_store(v4, (f32x4*)&Value[(size_t)j * CN + cb[m]]);
            f32x4 t4;
#pragma unroll
            for (int u = 0; u < 4; ++u) {
                float om;
                if (left) {
                    bool m1 = ((rs_i + rsc4[m][u] + dg_i + dgc4[m][u]) == 0.0f) && (cb[m] + u > j);
                    om = m1 ? 0.f : 1.f;
                } else {
                    om = rs_i;
                }
                t4[u] = v4[u] - om * 10000.f;
            }
            acc[m][n] = t4;
            mx = fmaxf(fmaxf(fmaxf(mx, t4[0]), t4[1]), fmaxf(t4[2], t4[3]));
        }
    }
    float sm = 0.f;
#pragma unroll
    for (int n = 0; n < 4; ++n)
#pragma unroll
        for (int m = 0; m < 4; ++m)
#pragma unroll
            for (int u = 0; u < 4; ++u) sm += __expf(acc[m][n][u] - mx);

    for (int o = 32; o; o >>= 1) {
        float om_ = __shfl_down(mx, o, 64);
        float os_ = __shfl_down(sm, o, 64);
        float nm = fmaxf(mx, om_);
        sm = sm * __expf(mx - nm) + os_ * __expf(om_ - nm);
        mx = nm;
    }
    if (!lane) { sRedM[w] = mx; sRedS[w] = sm; }
    __syncthreads();
    if (!tid) {
        float M = sRedM[0], S = sRedS[0];
        for (int i = 1; i < 4; ++i) {
            float nm = fmaxf(M, sRedM[i]);
            S = S * __expf(M - nm) + sRedS[i] * __expf(sRedM[i] - nm);
            M = nm;
        }
        int bid = blockIdx.y * gridDim.x + blockIdx.x;
        partials[2 * bid] = M;
        partials[2 * bid + 1] = S;
    }
}

// ---------- pass B: fused global softmax reduce + GEMM, write Poss (nt float4) ----------
__global__ __launch_bounds__(256) void k_valueB(const unsigned short* __restrict__ Gtb,
                                                const unsigned short* __restrict__ lwT,
                                                const float* __restrict__ lb,
                                                const float* __restrict__ rowsum, const float* __restrict__ deg,
                                                const float* __restrict__ partials, float* __restrict__ Poss) {
    // --- fused reduce: every block computes the identical (gmax, gsum) ---
    __shared__ float sRedM[4], sRedS[4], sG[2];
    {
        int tid0 = threadIdx.x;
        float mx = -INFINITY, sm = 0.f;
        for (int i = tid0; i < 2048; i += 256) {
            float m = partials[2 * i], s = partials[2 * i + 1];
            float nm = fmaxf(mx, m);
            sm = sm * __expf(mx - nm) + s * __expf(m - nm);
            mx = nm;
        }
        for (int o = 32; o; o >>= 1) {
            float om_ = __shfl_down(mx, o, 64);
            float os_ = __shfl_down(sm, o, 64);
            float nm = fmaxf(mx, om_);
            sm = sm * __expf(mx - nm) + os_ * __expf(om_ - nm);
            mx = nm;
        }
        int lane0 = tid0 & 63, w0 = tid0 >> 6;
        if (!lane0) { sRedM[w0] = mx; sRedS[w0] = sm; }
        __syncthreads();
        if (!tid0) {
            float M = sRedM[0], S = sRedS[0];
            for (int i = 1; i < 4; ++i) {
                float nm = fmaxf(M, sRedM[i]);
                S = S * __expf(M - nm) + sRedS[i] * __expf(sRedM[i] - nm);
                M = nm;
            }
            sG[0] = M; sG[1] = S;
        }
        __syncthreads();
    }
    float gmax = sG[0];
    float ginv = 1.0f / sG[1];

    GEMM_PROLOGUE()
#pragma unroll
    for (int n = 0; n < 4; ++n) {
        int j = j0 + n * 16 + lrow;
        float rs_i = rowsum[j], dg_i = deg[j];
#pragma unroll
        for (int m = 0; m < 4; ++m) {
            f32x4 v4 = acc[m][n] + lb4[m];
            f32x4 o4;
#pragma unroll
            for (int u = 0; u < 4; ++u) {
                float om;
                if (left) {
                    bool m1 = ((rs_i + rsc4[m][u] + dg_i + dgc4[m][u]) == 0.0f) && (cb[m] + u > j);
                    om = m1 ? 0.f : 1.f;
                } else {
                    om = rs_i;
                }
                o4[u] = __expf(v4[u] - om * 10000.f - gmax) * ginv;
            }
            __builtin_nontemporal_store(o4, (f32x4*)&Poss[(size_t)j * CN + cb[m]]);
        }
    }
}

extern "C" void kernel_launch(void* const* d_in, const int* in_sizes, int n_in,
                              void* d_out, int out_size, void* d_ws, size_t ws_size,
                              hipStream_t stream) {
    const float* h  = (const float*)d_in[0];
    const float* L  = (const float*)d_in[1];
    const float* W  = (const float*)d_in[2];
    const float* P  = (const float*)d_in[3];
    const float* N  = (const float*)d_in[4];
    const float* G  = (const float*)d_in[5];
    const float* tw = (const float*)d_in[6];
    const float* tb = (const float*)d_in[7];
    const float* lw = (const float*)d_in[8];
    const float* lb = (const float*)d_in[9];

    float* ws = (float*)d_ws;
    unsigned short* lwT = (unsigned short*)(ws + WS_LWT);
    unsigned short* Gtb = (unsigned short*)(ws + WS_GTB);
    float* rowsum = ws + WS_ROWSUM;
    float* deg    = ws + WS_DEG;
    float* norm   = ws + WS_NORM;
    float* X      = ws + WS_X;
    float* f1     = ws + WS_F1;
    float* part   = ws + WS_PART;
    unsigned* bar = (unsigned*)(ws + WS_BAR);

    float* Value = (float*)d_out;
    float* Poss  = Value + (size_t)JN * CN;

    unsigned long long* bitR = (unsigned long long*)(Poss + PS_BITR);
    float* colpart = Poss + PS_COLPART;
    float* p1      = Poss + PS_P1;
    float* p2      = Poss + PS_P2;

    k_front  <<<2 * JN + 128 + 1, 256, 0, stream>>>(G, h, L, W, P, N, lw, rowsum, bitR, X, lwT, bar);
    k_middle <<<256, 256, 0, stream>>>(bitR, X, tw, tb, colpart, deg, norm, f1, p1, p2, Gtb, bar);
    k_valueA <<<dim3(32, 64), 256, 0, stream>>>(Gtb, lwT, lb, rowsum, deg, Value, part);
    k_valueB <<<dim3(32, 64), 256, 0, stream>>>(Gtb, lwT, lb, rowsum, deg, part, Poss);
}

// Round 9
// 149.525 us; speedup vs baseline: 1.4821x; 1.4821x over previous
//
#include <hip/hip_runtime.h>
#include <math.h>

#define JN 4096
#define CN 8192

typedef __attribute__((ext_vector_type(8))) short short8;
typedef __attribute__((ext_vector_type(4))) short short4v;
typedef __attribute__((ext_vector_type(4))) float f32x4;

// ---- d_ws layout (float offsets) ----
#define WS_LWT    0        // bf16 8192*64 = 262144 float slots
#define WS_GTB    262144   // bf16 4096*64 = 131072 float slots
#define WS_ROWSUM 393216   // 4096
#define WS_DEG    397312   // 4096 (atomic-accumulated; zeroed by k_front each launch)
#define WS_NORM   401408   // 4096
#define WS_X      405504   // 24576
#define WS_F1     430080   // 24576
#define WS_PART   454656   // 2*2048

// ---- scratch inside the Poss half of d_out (float offsets within Poss) ----
// All consumed before k_valueB overwrites the Poss region.
#define PS_BITR    0        // uint64[4096][64] = 2 MiB
#define PS_P1      524288   // 16*24576
#define PS_P2      917504   // 16*24576

__device__ __forceinline__ unsigned short f2bf(float x) {
    unsigned int u = __float_as_uint(x);
    u += 0x7fffu + ((u >> 16) & 1u);   // RNE
    return (unsigned short)(u >> 16);
}

__device__ __forceinline__ float gt_val(const float* __restrict__ x, const float* __restrict__ a,
                                        const float* __restrict__ b, const float* __restrict__ tw,
                                        float acc, int f) {
#pragma unroll
    for (int k = 0; k < 6; ++k) acc += x[k] * tw[k * 64 + f];
#pragma unroll
    for (int k = 0; k < 6; ++k) acc += a[k] * tw[(k + 6) * 64 + f];
#pragma unroll
    for (int k = 0; k < 6; ++k) acc += b[k] * tw[(k + 12) * 64 + f];
    return acc;
}

// ---------- front: G pass (rowsum+bitpack) | rank | lwT transpose | deg zero ----------
// bit layout: col cu -> word (cu>>10)*16 + ((cu>>8)&3)*4 + (cu&3), bit (cu>>2)&63
__global__ __launch_bounds__(256) void k_front(const float* __restrict__ G,
                                               const float* __restrict__ h, const float* __restrict__ L,
                                               const float* __restrict__ Wp, const float* __restrict__ Pp,
                                               const float* __restrict__ Np,
                                               const float* __restrict__ lw,
                                               float* __restrict__ rowsum,
                                               unsigned long long* __restrict__ bitR,
                                               float* __restrict__ X,
                                               unsigned short* __restrict__ lwT,
                                               float* __restrict__ deg) {
    __shared__ float redf[4];
    __shared__ int redi[4];
    __shared__ float s_t[64][65];
    int wv = threadIdx.x >> 6, lane = threadIdx.x & 63;
    if (blockIdx.x < JN) {
        int row = blockIdx.x;
        const f32x4* g4 = (const f32x4*)(G + (size_t)row * CN);
        unsigned long long* brow = bitR + (size_t)row * 64;
        float s = 0.f;
#pragma unroll
        for (int i = 0; i < 4; ++i) {          // left half
            f32x4 v = __builtin_nontemporal_load(&g4[i * 256 + wv * 64 + lane]);
            s += v[0] + v[1] + v[2] + v[3];
            unsigned long long b0 = __ballot(v[0] != 0.f);
            unsigned long long b1 = __ballot(v[1] != 0.f);
            unsigned long long b2 = __ballot(v[2] != 0.f);
            unsigned long long b3 = __ballot(v[3] != 0.f);
            if (!lane) {
                int base = i * 16 + wv * 4;
                brow[base] = b0; brow[base + 1] = b1; brow[base + 2] = b2; brow[base + 3] = b3;
            }
        }
#pragma unroll
        for (int i = 4; i < 8; ++i) {          // right half
            f32x4 v = __builtin_nontemporal_load(&g4[i * 256 + wv * 64 + lane]);
            s += v[0] + v[1] + v[2] + v[3];
        }
        for (int o = 32; o; o >>= 1) s += __shfl_down(s, o, 64);
        if (!lane) redf[wv] = s;
        __syncthreads();
        if (!threadIdx.x) rowsum[row] = redf[0] + redf[1] + redf[2] + redf[3];
    } else if (blockIdx.x < 2 * JN) {
        int i = blockIdx.x - JN;
        float hi = h[i];
        int cnt = 0;
        for (int j = threadIdx.x; j < JN; j += 256) {
            float hj = h[j];
            cnt += (hj > hi) || (hj == hi && j < i);   // stable argsort(-h) rank
        }
        for (int o = 32; o; o >>= 1) cnt += __shfl_down(cnt, o, 64);
        if (!lane) redi[wv] = cnt;
        __syncthreads();
        if (!threadIdx.x) {
            int r = redi[0] + redi[1] + redi[2] + redi[3];
            float* xr = X + r * 6;
            xr[0] = hi; xr[1] = L[i]; xr[2] = *Wp; xr[3] = *Pp; xr[4] = *Np; xr[5] = 1.f;
        }
    } else if (blockIdx.x < 2 * JN + 128) {
        int c0 = (blockIdx.x - 2 * JN) * 64;
        for (int t = threadIdx.x; t < 4096; t += 256) {
            int f = t >> 6, cc = t & 63;
            s_t[f][cc] = lw[(size_t)f * CN + c0 + cc];
        }
        __syncthreads();
        for (int q = threadIdx.x; q < 512; q += 256) {
            int c = q >> 3, kc = q & 7;
            short8 pack;
#pragma unroll
            for (int i = 0; i < 8; ++i) pack[i] = (short)f2bf(s_t[kc * 8 + i][c]);
            *(short8*)(lwT + ((size_t)(c0 + c)) * 64 + kc * 8) = pack;
        }
    } else {
        for (int t = threadIdx.x; t < JN; t += 256) deg[t] = 0.f;   // zero atomic target
    }
}

// ---------- column sums from bitmask -> exact atomic adds into deg ----------
__global__ __launch_bounds__(256) void k_colsum_bits(const unsigned long long* __restrict__ bitR,
                                                     float* __restrict__ deg) {
    __shared__ unsigned long long s_bits[256][4];
    int bx = blockIdx.x, r0 = blockIdx.y * 256;
    int tid = threadIdx.x;
    for (int t = tid; t < 1024; t += 256) {
        int r = t >> 2, wl = t & 3;
        s_bits[r][wl] = bitR[(size_t)(r0 + r) * 64 + bx * 4 + wl];
    }
    __syncthreads();
    int wl = tid & 3, bit = tid >> 2;
    int cnt = 0;
    for (int r = 0; r < 256; ++r)
        cnt += (int)((s_bits[r][wl] >> bit) & 1ull);
    atomicAdd(&deg[bx * 256 + tid], (float)cnt);   // integer-valued fp32: exact, order-independent
}

// ---------- prop1: norm from deg inline, stage Xn, emit p1; bx==0 writes norm ----------
__global__ __launch_bounds__(256) void k_prop1(const unsigned long long* __restrict__ bitR,
                                               const float* __restrict__ X,
                                               const float* __restrict__ deg,
                                               float* __restrict__ norm,
                                               float* __restrict__ part) {
    __shared__ unsigned long long s_bits[256][4];
    __shared__ float s_in[1536];
    __shared__ float s_norm[256];
    int bx = blockIdx.x, r0 = blockIdx.y * 256;
    int tid = threadIdx.x;
    {
        float d = deg[r0 + tid];
        float dc = d < 1.f ? 1.f : d;
        float nv = rsqrtf(dc);
        s_norm[tid] = nv;
        if (bx == 0) norm[r0 + tid] = nv;
    }
    for (int t = tid; t < 1024; t += 256) {
        int r = t >> 2, wl = t & 3;
        s_bits[r][wl] = bitR[(size_t)(r0 + r) * 64 + bx * 4 + wl];
    }
    __syncthreads();
    for (int t = tid; t < 1536; t += 256)
        s_in[t] = X[r0 * 6 + t] * s_norm[t / 6];
    __syncthreads();
    int wl = tid & 3, bit = tid >> 2;
    float a0 = 0, a1 = 0, a2 = 0, a3 = 0, a4 = 0, a5 = 0;
    for (int r = 0; r < 256; ++r) {
        float g = (float)((s_bits[r][wl] >> bit) & 1ull);
        const float* x = &s_in[r * 6];
        a0 += g * x[0]; a1 += g * x[1]; a2 += g * x[2];
        a3 += g * x[3]; a4 += g * x[4]; a5 += g * x[5];
    }
    float* o = part + ((size_t)blockIdx.y * JN + bx * 256 + tid) * 6;
    o[0] = a0; o[1] = a1; o[2] = a2; o[3] = a3; o[4] = a4; o[5] = a5;
}

// ---------- prop2: reduce p1 + *norm inline, emit p2; bx==0 writes f1 ----------
__global__ __launch_bounds__(256) void k_prop2(const unsigned long long* __restrict__ bitR,
                                               const float* __restrict__ p1, const float* __restrict__ norm,
                                               float* __restrict__ f1, float* __restrict__ part) {
    __shared__ unsigned long long s_bits[256][4];
    __shared__ float s_in[1536];
    int bx = blockIdx.x, r0 = blockIdx.y * 256;
    int tid = threadIdx.x;
    for (int t = tid; t < 1024; t += 256) {
        int r = t >> 2, wl = t & 3;
        s_bits[r][wl] = bitR[(size_t)(r0 + r) * 64 + bx * 4 + wl];
    }
    for (int t = tid; t < 1536; t += 256) {
        float s = 0.f;
        for (int ch = 0; ch < 16; ++ch) s += p1[(size_t)ch * 24576 + r0 * 6 + t];
        int row = r0 + t / 6;
        float n = norm[row];
        float f1v = s * n;
        if (bx == 0) f1[r0 * 6 + t] = f1v;
        s_in[t] = f1v * n;
    }
    __syncthreads();
    int wl = tid & 3, bit = tid >> 2;
    float a0 = 0, a1 = 0, a2 = 0, a3 = 0, a4 = 0, a5 = 0;
    for (int r = 0; r < 256; ++r) {
        float g = (float)((s_bits[r][wl] >> bit) & 1ull);
        const float* x = &s_in[r * 6];
        a0 += g * x[0]; a1 += g * x[1]; a2 += g * x[2];
        a3 += g * x[3]; a4 += g * x[4]; a5 += g * x[5];
    }
    float* o = part + ((size_t)blockIdx.y * JN + bx * 256 + tid) * 6;
    o[0] = a0; o[1] = a1; o[2] = a2; o[3] = a3; o[4] = a4; o[5] = a5;
}

// ---------- Gt: reduce p2 -> f2 rows inline, compute Gtb bf16 (once) ----------
__global__ __launch_bounds__(256) void k_gt(const float* __restrict__ p2, const float* __restrict__ norm,
                                            const float* __restrict__ f1, const float* __restrict__ X,
                                            const float* __restrict__ tw, const float* __restrict__ tb,
                                            unsigned short* __restrict__ Gtb) {
    __shared__ float s_x[64 * 6], s_f1[64 * 6], s_f2[64 * 6];
    __shared__ float s_tw[18 * 64], s_tb[64];
    int j0 = blockIdx.x * 64, tid = threadIdx.x;
    for (int t = tid; t < 1152; t += 256) s_tw[t] = tw[t];
    if (tid < 64) s_tb[tid] = tb[tid];
    for (int t = tid; t < 384; t += 256) {
        s_x[t] = X[j0 * 6 + t];
        s_f1[t] = f1[j0 * 6 + t];
        float s = 0.f;
        for (int ch = 0; ch < 16; ++ch) s += p2[(size_t)ch * 24576 + j0 * 6 + t];
        s_f2[t] = s * norm[j0 + t / 6];
    }
    __syncthreads();
    int row = tid & 63, fg = tid >> 6;
    float xv[6], av[6], bv[6];
#pragma unroll
    for (int k = 0; k < 6; ++k) {
        xv[k] = s_x[row * 6 + k]; av[k] = s_f1[row * 6 + k]; bv[k] = s_f2[row * 6 + k];
    }
    short8 p0, p1v;
#pragma unroll
    for (int i = 0; i < 16; ++i) {
        int f = fg * 16 + i;
        float acc = gt_val(xv, av, bv, s_tw, s_tb[f], f);
        unsigned short u = f2bf(acc);
        if (i < 8) p0[i] = (short)u; else p1v[i - 8] = (short)u;
    }
    *(short8*)(Gtb + (size_t)(j0 + row) * 64 + fg * 16) = p0;
    *(short8*)(Gtb + (size_t)(j0 + row) * 64 + fg * 16 + 8) = p1v;
}

// GEMM decls: sGt/sW = 40960 B exactly (4 blocks/CU); reduction scratch overlays sGt
// (dead after the MFMA loop; GEMM_BODY ends with a __syncthreads() to guard reuse).
#define GEMM_DECLS()                                                                      \
    __shared__ unsigned short sGt[64 * 64];                                               \
    __shared__ unsigned short sW[256 * 64];                                               \
    float* sRedM = (float*)sGt;                                                           \
    float* sRedS = ((float*)sGt) + 4;                                                     \
    float* sG    = ((float*)sGt) + 8;                                                     \
    (void)sRedM; (void)sRedS; (void)sG;

#define GEMM_BODY()                                                                       \
    int j0 = blockIdx.y * 64, c0 = blockIdx.x * 256, tid = threadIdx.x;                   \
    for (int q = tid; q < 2048; q += 256) {                                               \
        int col = q >> 3, off = q & 7;                                                    \
        short8 v = *(const short8*)(lwT + ((size_t)(c0 + col)) * 64 + off * 8);           \
        int byte = (col * 128 + off * 16) ^ ((col & 7) << 4);                             \
        *(short8*)((char*)sW + byte) = v;                                                 \
    }                                                                                     \
    for (int q = tid; q < 512; q += 256) {                                                \
        int row = q >> 3, off = q & 7;                                                    \
        short8 v = *(const short8*)(Gtb + ((size_t)(j0 + row)) * 64 + off * 8);           \
        int byte = (row * 128 + off * 16) ^ ((row & 7) << 4);                             \
        *(short8*)((char*)sGt + byte) = v;                                                \
    }                                                                                     \
    __syncthreads();                                                                      \
    int lane = tid & 63, w = tid >> 6;                                                    \
    int lrow = lane & 15, kg = lane >> 4;                                                 \
    f32x4 acc[4][4]; /* [m over c][n over j] */                                           \
    for (int m = 0; m < 4; ++m)                                                           \
        for (int n = 0; n < 4; ++n) acc[m][n] = (f32x4){0.f, 0.f, 0.f, 0.f};              \
    for (int ks = 0; ks < 2; ++ks) {                                                      \
        int kb = ks * 64 + kg * 16;                                                       \
        short8 wf[4], gf[4];                                                              \
        for (int m = 0; m < 4; ++m) {                                                     \
            int col = w * 64 + m * 16 + lrow;                                             \
            wf[m] = *(const short8*)((const char*)sW + ((col * 128 + kb) ^ ((col & 7) << 4))); \
        }                                                                                 \
        for (int n = 0; n < 4; ++n) {                                                     \
            int row = n * 16 + lrow;                                                      \
            gf[n] = *(const short8*)((const char*)sGt + ((row * 128 + kb) ^ ((row & 7) << 4))); \
        }                                                                                 \
        for (int m = 0; m < 4; ++m)                                                       \
            for (int n = 0; n < 4; ++n)                                                   \
                acc[m][n] = __builtin_amdgcn_mfma_f32_16x16x32_bf16(wf[m], gf[n], acc[m][n], 0, 0, 0); \
    }                                                                                     \
    __syncthreads(); /* sGt dead beyond this point -> sRed overlay safe */                \
    bool left = (c0 < JN);                                                                \
    int cb[4]; f32x4 lb4[4], rsc4[4], dgc4[4];                                            \
    for (int m = 0; m < 4; ++m) {                                                         \
        cb[m] = c0 + w * 64 + m * 16 + kg * 4;                                            \
        lb4[m] = *(const f32x4*)&lb[cb[m]];                                               \
        if (left) { rsc4[m] = *(const f32x4*)&rowsum[cb[m]]; dgc4[m] = *(const f32x4*)&deg[cb[m]]; } \
        else      { rsc4[m] = (f32x4){0,0,0,0}; dgc4[m] = (f32x4){0,0,0,0}; }             \
    }

// ---------- pass A: Value write (nt float4) + two-pass softmax partials ----------
__global__ __launch_bounds__(256) void k_valueA(const unsigned short* __restrict__ Gtb,
                                                const unsigned short* __restrict__ lwT,
                                                const float* __restrict__ lb,
                                                const float* __restrict__ rowsum, const float* __restrict__ deg,
                                                float* __restrict__ Value, float* __restrict__ partials) {
    GEMM_DECLS()
    GEMM_BODY()

    float mx = -INFINITY;
#pragma unroll
    for (int n = 0; n < 4; ++n) {
        int j = j0 + n * 16 + lrow;
        float rs_i = rowsum[j], dg_i = deg[j];
#pragma unroll
        for (int m = 0; m < 4; ++m) {
            f32x4 v4 = acc[m][n] + lb4[m];
            __builtin_nontemporal_store(v4, (f32x4*)&Value[(size_t)j * CN + cb[m]]);
            f32x4 t4;
#pragma unroll
            for (int u = 0; u < 4; ++u) {
                float om;
                if (left) {
                    bool m1 = ((rs_i + rsc4[m][u] + dg_i + dgc4[m][u]) == 0.0f) && (cb[m] + u > j);
                    om = m1 ? 0.f : 1.f;
                } else {
                    om = rs_i;
                }
                t4[u] = v4[u] - om * 10000.f;
            }
            acc[m][n] = t4;
            mx = fmaxf(fmaxf(fmaxf(mx, t4[0]), t4[1]), fmaxf(t4[2], t4[3]));
        }
    }
    float sm = 0.f;
#pragma unroll
    for (int n = 0; n < 4; ++n)
#pragma unroll
        for (int m = 0; m < 4; ++m)
#pragma unroll
            for (int u = 0; u < 4; ++u) sm += __expf(acc[m][n][u] - mx);

    for (int o = 32; o; o >>= 1) {
        float om_ = __shfl_down(mx, o, 64);
        float os_ = __shfl_down(sm, o, 64);
        float nm = fmaxf(mx, om_);
        sm = sm * __expf(mx - nm) + os_ * __expf(om_ - nm);
        mx = nm;
    }
    if (!lane) { sRedM[w] = mx; sRedS[w] = sm; }
    __syncthreads();
    if (!tid) {
        float M = sRedM[0], S = sRedS[0];
        for (int i = 1; i < 4; ++i) {
            float nm = fmaxf(M, sRedM[i]);
            S = S * __expf(M - nm) + sRedS[i] * __expf(sRedM[i] - nm);
            M = nm;
        }
        int bid = blockIdx.y * gridDim.x + blockIdx.x;
        partials[2 * bid] = M;
        partials[2 * bid + 1] = S;
    }
}

// ---------- pass B: fused global softmax reduce + GEMM, write Poss (nt float4) ----------
__global__ __launch_bounds__(256) void k_valueB(const unsigned short* __restrict__ Gtb,
                                                const unsigned short* __restrict__ lwT,
                                                const float* __restrict__ lb,
                                                const float* __restrict__ rowsum, const float* __restrict__ deg,
                                                const float* __restrict__ partials, float* __restrict__ Poss) {
    GEMM_DECLS()
    // --- fused reduce: every block computes the identical (gmax, gsum) ---
    {
        int tid0 = threadIdx.x;
        float mx = -INFINITY, sm = 0.f;
        for (int i = tid0; i < 2048; i += 256) {
            float m = partials[2 * i], s = partials[2 * i + 1];
            float nm = fmaxf(mx, m);
            sm = sm * __expf(mx - nm) + s * __expf(m - nm);
            mx = nm;
        }
        for (int o = 32; o; o >>= 1) {
            float om_ = __shfl_down(mx, o, 64);
            float os_ = __shfl_down(sm, o, 64);
            float nm = fmaxf(mx, om_);
            sm = sm * __expf(mx - nm) + os_ * __expf(om_ - nm);
            mx = nm;
        }
        int lane0 = tid0 & 63, w0 = tid0 >> 6;
        if (!lane0) { sRedM[w0] = mx; sRedS[w0] = sm; }
        __syncthreads();
        if (!tid0) {
            float M = sRedM[0], S = sRedS[0];
            for (int i = 1; i < 4; ++i) {
                float nm = fmaxf(M, sRedM[i]);
                S = S * __expf(M - nm) + sRedS[i] * __expf(sRedM[i] - nm);
                M = nm;
            }
            sG[0] = M; sG[1] = S;
        }
        __syncthreads();
    }
    float gmax = sG[0];
    float ginv = 1.0f / sG[1];
    __syncthreads();   // all threads have gmax/ginv in regs before staging clobbers sGt

    GEMM_BODY()
#pragma unroll
    for (int n = 0; n < 4; ++n) {
        int j = j0 + n * 16 + lrow;
        float rs_i = rowsum[j], dg_i = deg[j];
#pragma unroll
        for (int m = 0; m < 4; ++m) {
            f32x4 v4 = acc[m][n] + lb4[m];
            f32x4 o4;
#pragma unroll
            for (int u = 0; u < 4; ++u) {
                float om;
                if (left) {
                    bool m1 = ((rs_i + rsc4[m][u] + dg_i + dgc4[m][u]) == 0.0f) && (cb[m] + u > j);
                    om = m1 ? 0.f : 1.f;
                } else {
                    om = rs_i;
                }
                o4[u] = __expf(v4[u] - om * 10000.f - gmax) * ginv;
            }
            __builtin_nontemporal_store(o4, (f32x4*)&Poss[(size_t)j * CN + cb[m]]);
        }
    }
}

extern "C" void kernel_launch(void* const* d_in, const int* in_sizes, int n_in,
                              void* d_out, int out_size, void* d_ws, size_t ws_size,
                              hipStream_t stream) {
    const float* h  = (const float*)d_in[0];
    const float* L  = (const float*)d_in[1];
    const float* W  = (const float*)d_in[2];
    const float* P  = (const float*)d_in[3];
    const float* N  = (const float*)d_in[4];
    const float* G  = (const float*)d_in[5];
    const float* tw = (const float*)d_in[6];
    const float* tb = (const float*)d_in[7];
    const float* lw = (const float*)d_in[8];
    const float* lb = (const float*)d_in[9];

    float* ws = (float*)d_ws;
    unsigned short* lwT = (unsigned short*)(ws + WS_LWT);
    unsigned short* Gtb = (unsigned short*)(ws + WS_GTB);
    float* rowsum = ws + WS_ROWSUM;
    float* deg    = ws + WS_DEG;
    float* norm   = ws + WS_NORM;
    float* X      = ws + WS_X;
    float* f1     = ws + WS_F1;
    float* part   = ws + WS_PART;

    float* Value = (float*)d_out;
    float* Poss  = Value + (size_t)JN * CN;

    unsigned long long* bitR = (unsigned long long*)(Poss + PS_BITR);
    float* p1      = Poss + PS_P1;
    float* p2      = Poss + PS_P2;

    k_front      <<<2 * JN + 129, 256, 0, stream>>>(G, h, L, W, P, N, lw, rowsum, bitR, X, lwT, deg);
    k_colsum_bits<<<dim3(16, 16), 256, 0, stream>>>(bitR, deg);
    k_prop1      <<<dim3(16, 16), 256, 0, stream>>>(bitR, X, deg, norm, p1);
    k_prop2      <<<dim3(16, 16), 256, 0, stream>>>(bitR, p1, norm, f1, p2);
    k_gt         <<<64, 256, 0, stream>>>(p2, norm, f1, X, tw, tb, Gtb);
    k_valueA     <<<dim3(32, 64), 256, 0, stream>>>(Gtb, lwT, lb, rowsum, deg, Value, part);
    k_valueB     <<<dim3(32, 64), 256, 0, stream>>>(Gtb, lwT, lb, rowsum, deg, part, Poss);
}